// Round 9
// baseline (781.331 us; speedup 1.0000x reference)
//
#include <hip/hip_runtime.h>
#include <hip/hip_bf16.h>

#define N_NODES 50000
#define N_EDGES 800000
#define F_IN    128
#define H_DIM   256
#define G_NUM   64
#define A_DIM   8

typedef __attribute__((ext_vector_type(8))) short short8v;
typedef __attribute__((ext_vector_type(4))) float float4v;
typedef __attribute__((ext_vector_type(2))) float float2v;

__device__ __forceinline__ float b2f(unsigned short u) {
    return __uint_as_float(((unsigned int)u) << 16);
}
__device__ __forceinline__ unsigned short f2b(float v) {
    return __hip_bfloat16_raw(__float2bfloat16(v)).x;
}
__device__ __forceinline__ unsigned char f2fp8(float v) {
    return (unsigned char)(__builtin_amdgcn_cvt_pk_fp8_f32(v, v, 0, false) & 0xff);
}
__device__ __forceinline__ void accf8x4(float* a, unsigned int u, float w) {
    float2v lo = __builtin_amdgcn_cvt_pk_f32_fp8((int)u, false);
    float2v hi = __builtin_amdgcn_cvt_pk_f32_fp8((int)u, true);
    a[0] = fmaf(w, lo.x, a[0]); a[1] = fmaf(w, lo.y, a[1]);
    a[2] = fmaf(w, hi.x, a[2]); a[3] = fmaf(w, hi.y, a[3]);
}
__device__ __forceinline__ void accf8x16(float* a, uint4 v, float w) {
    accf8x4(a + 0, v.x, w); accf8x4(a + 4, v.y, w);
    accf8x4(a + 8, v.z, w); accf8x4(a + 12, v.w, w);
}
__device__ __forceinline__ void decf8x16(float* s, uint4 v) {
    float2v t;
    t = __builtin_amdgcn_cvt_pk_f32_fp8((int)v.x, false); s[0] = t.x; s[1] = t.y;
    t = __builtin_amdgcn_cvt_pk_f32_fp8((int)v.x, true);  s[2] = t.x; s[3] = t.y;
    t = __builtin_amdgcn_cvt_pk_f32_fp8((int)v.y, false); s[4] = t.x; s[5] = t.y;
    t = __builtin_amdgcn_cvt_pk_f32_fp8((int)v.y, true);  s[6] = t.x; s[7] = t.y;
    t = __builtin_amdgcn_cvt_pk_f32_fp8((int)v.z, false); s[8] = t.x; s[9] = t.y;
    t = __builtin_amdgcn_cvt_pk_f32_fp8((int)v.z, true);  s[10] = t.x; s[11] = t.y;
    t = __builtin_amdgcn_cvt_pk_f32_fp8((int)v.w, false); s[12] = t.x; s[13] = t.y;
    t = __builtin_amdgcn_cvt_pk_f32_fp8((int)v.w, true);  s[14] = t.x; s[15] = t.y;
}

// ---------------- CSR build ----------------

__global__ void indeg_kernel(const int* __restrict__ dst, int* __restrict__ indeg, int e) {
    int i = blockIdx.x * blockDim.x + threadIdx.x;
    if (i < e) atomicAdd(&indeg[dst[i]], 1);
}

__global__ __launch_bounds__(256) void scan1_kernel(const int* __restrict__ in,
                                                    int* __restrict__ out,
                                                    int* __restrict__ bsum,
                                                    float* __restrict__ dinv, int n) {
    __shared__ int tile[256];
    int b = blockIdx.x, t = threadIdx.x, i = b * 256 + t;
    int v = (i < n) ? in[i] : 0;
    if (i < n) dinv[i] = rsqrtf((float)v + 1.0f);
    tile[t] = v;
    __syncthreads();
    #pragma unroll
    for (int o = 1; o < 256; o <<= 1) {
        int add = (t >= o) ? tile[t - o] : 0;
        __syncthreads();
        tile[t] += add;
        __syncthreads();
    }
    if (i < n) out[i] = tile[t] - v;
    if (t == 255) bsum[b] = tile[255];
}

__global__ __launch_bounds__(256) void scan2_kernel(int* __restrict__ bsum, int nb,
                                                    const int* __restrict__ batch,
                                                    int* __restrict__ gstart,
                                                    float* __restrict__ pooled) {
    __shared__ int tile[256];
    int t = threadIdx.x;
    int v = (t < nb) ? bsum[t] : 0;
    tile[t] = v;
    __syncthreads();
    #pragma unroll
    for (int o = 1; o < 256; o <<= 1) {
        int add = (t >= o) ? tile[t - o] : 0;
        __syncthreads();
        tile[t] += add;
        __syncthreads();
    }
    if (t < nb) bsum[t] = tile[t] - v;
    if (t <= G_NUM) {
        int lo = 0, hi = N_NODES;
        while (lo < hi) {
            int mid = (lo + hi) >> 1;
            if (batch[mid] < t) lo = mid + 1; else hi = mid;
        }
        gstart[t] = lo;
    }
    for (int i = t; i < G_NUM * H_DIM; i += 256) pooled[i] = 0.f;
}

__global__ __launch_bounds__(256) void scan3_kernel(int* __restrict__ out,
                                                    const int* __restrict__ bsum,
                                                    int* __restrict__ pos, int n) {
    int i = blockIdx.x * blockDim.x + threadIdx.x;
    if (i < n) {
        int r = out[i] + bsum[i >> 8];
        out[i] = r;
        pos[i] = r;
    }
    if (i == 0) out[n] = N_EDGES;
}

__global__ void place_kernel(const int* __restrict__ src, const int* __restrict__ dst,
                             int* __restrict__ pos, int* __restrict__ csr_src, int e) {
    int i = blockIdx.x * blockDim.x + threadIdx.x;
    if (i < e) {
        int s = src[i], d = dst[i];
        int slot = atomicAdd(&pos[d], 1);
        csr_src[slot] = s;
    }
}

// ------- conversions: x -> fp8, W1/W2/W3 -> bf16 transposed -------

__global__ void conv_fused(const float4* __restrict__ x, unsigned int* __restrict__ xb8,
                           const float* __restrict__ W1, unsigned short* __restrict__ Wt1,
                           const float* __restrict__ W2, unsigned short* __restrict__ Wt2,
                           const float* __restrict__ W3, unsigned short* __restrict__ Wt3) {
    const int n_x  = N_NODES * F_IN / 4;
    const int n_w1 = F_IN * H_DIM;
    const int n_w2 = H_DIM * H_DIM;
    int i = blockIdx.x * blockDim.x + threadIdx.x;
    if (i < n_x) {
        float4 v = x[i];
        unsigned int pk = (unsigned int)__builtin_amdgcn_cvt_pk_fp8_f32(v.x, v.y, 0, false);
        pk = (unsigned int)__builtin_amdgcn_cvt_pk_fp8_f32(v.z, v.w, (int)pk, true);
        xb8[i] = pk;
    } else if (i < n_x + n_w1) {
        int j = i - n_x;
        int k = j / H_DIM, n = j % H_DIM;
        Wt1[(size_t)n * F_IN + k] = f2b(W1[j]);
    } else if (i < n_x + n_w1 + n_w2) {
        int j = i - n_x - n_w1;
        int k = j / H_DIM, n = j % H_DIM;
        Wt2[(size_t)n * H_DIM + k] = f2b(W2[j]);
    } else if (i < n_x + n_w1 + 2 * n_w2) {
        int j = i - n_x - n_w1 - n_w2;
        int k = j / H_DIM, n = j % H_DIM;
        Wt3[(size_t)n * H_DIM + k] = f2b(W3[j]);
    }
}

// ------- bf16 MFMA GEMM, BN=256, fp8 output -------

#define SK 40

__global__ __launch_bounds__(512) void gemm_f8(const unsigned short* __restrict__ A,
                                               const unsigned short* __restrict__ Bt,
                                               unsigned char* __restrict__ C8,
                                               int M, int K) {
    __shared__ unsigned short As[128][SK];
    __shared__ unsigned short Bs[256][SK];
    int t = threadIdx.x;
    int wave = t >> 6, lane = t & 63;
    int wm0 = (wave & 1) * 64, wn0 = (wave >> 1) * 64;
    int bm = blockIdx.x * 128;
    int l15 = lane & 15, lq = lane >> 4;
    float4v acc[4][4];
    #pragma unroll
    for (int i = 0; i < 4; i++)
        #pragma unroll
        for (int j = 0; j < 4; j++)
            acc[i][j] = (float4v){0.f, 0.f, 0.f, 0.f};

    for (int k0 = 0; k0 < K; k0 += 32) {
        {
            int row = t >> 2, koff = (t & 3) * 8;
            uint4 va = make_uint4(0u, 0u, 0u, 0u);
            if (bm + row < M)
                va = *(const uint4*)(A + (size_t)(bm + row) * K + k0 + koff);
            *(uint4*)&As[row][koff] = va;
        }
        #pragma unroll
        for (int h = 0; h < 2; h++) {
            int c = t + h * 512;
            int row = c >> 2, koff = (c & 3) * 8;
            uint4 vb = *(const uint4*)(Bt + (size_t)row * K + k0 + koff);
            *(uint4*)&Bs[row][koff] = vb;
        }
        __syncthreads();
        short8v af[4], bf[4];
        #pragma unroll
        for (int i = 0; i < 4; i++) {
            af[i] = *(const short8v*)&As[wm0 + i * 16 + l15][lq * 8];
            bf[i] = *(const short8v*)&Bs[wn0 + i * 16 + l15][lq * 8];
        }
        #pragma unroll
        for (int i = 0; i < 4; i++)
            #pragma unroll
            for (int j = 0; j < 4; j++)
                acc[i][j] = __builtin_amdgcn_mfma_f32_16x16x32_bf16(af[i], bf[j], acc[i][j], 0, 0, 0);
        __syncthreads();
    }
    #pragma unroll
    for (int i = 0; i < 4; i++) {
        #pragma unroll
        for (int r = 0; r < 4; r++) {
            int row = bm + wm0 + i * 16 + lq * 4 + r;
            if (row < M) {
                #pragma unroll
                for (int j = 0; j < 4; j++) {
                    int col = wn0 + j * 16 + l15;
                    C8[(size_t)row * H_DIM + col] = f2fp8(acc[i][j][r]);
                }
            }
        }
    }
}

// ------- GEMM1 with fused bias+LayerNorm+ReLU epilogue, bf16 output -------

__global__ __launch_bounds__(512) void gemm_ln(const unsigned short* __restrict__ A,
                                               const unsigned short* __restrict__ Bt,
                                               unsigned short* __restrict__ C,
                                               const float* __restrict__ bias,
                                               const float* __restrict__ gamma,
                                               const float* __restrict__ beta,
                                               int M, int K) {
    __shared__ unsigned short As[128][SK];
    __shared__ unsigned short Bs[256][SK];
    __shared__ float red_s[4][128];
    __shared__ float red_ss[4][128];
    int t = threadIdx.x;
    int wave = t >> 6, lane = t & 63;
    int wm0 = (wave & 1) * 64, wn0 = (wave >> 1) * 64;
    int wn_idx = wave >> 1;
    int bm = blockIdx.x * 128;
    int l15 = lane & 15, lq = lane >> 4;
    float4v acc[4][4];
    #pragma unroll
    for (int i = 0; i < 4; i++)
        #pragma unroll
        for (int j = 0; j < 4; j++)
            acc[i][j] = (float4v){0.f, 0.f, 0.f, 0.f};

    for (int k0 = 0; k0 < K; k0 += 32) {
        {
            int row = t >> 2, koff = (t & 3) * 8;
            uint4 va = make_uint4(0u, 0u, 0u, 0u);
            if (bm + row < M)
                va = *(const uint4*)(A + (size_t)(bm + row) * K + k0 + koff);
            *(uint4*)&As[row][koff] = va;
        }
        #pragma unroll
        for (int h = 0; h < 2; h++) {
            int c = t + h * 512;
            int row = c >> 2, koff = (c & 3) * 8;
            uint4 vb = *(const uint4*)(Bt + (size_t)row * K + k0 + koff);
            *(uint4*)&Bs[row][koff] = vb;
        }
        __syncthreads();
        short8v af[4], bf[4];
        #pragma unroll
        for (int i = 0; i < 4; i++) {
            af[i] = *(const short8v*)&As[wm0 + i * 16 + l15][lq * 8];
            bf[i] = *(const short8v*)&Bs[wn0 + i * 16 + l15][lq * 8];
        }
        #pragma unroll
        for (int i = 0; i < 4; i++)
            #pragma unroll
            for (int j = 0; j < 4; j++)
                acc[i][j] = __builtin_amdgcn_mfma_f32_16x16x32_bf16(af[i], bf[j], acc[i][j], 0, 0, 0);
        __syncthreads();
    }

    float bcol[4], gcol[4], becol[4];
    #pragma unroll
    for (int j = 0; j < 4; j++) {
        int col = wn0 + j * 16 + l15;
        bcol[j] = bias[col]; gcol[j] = gamma[col]; becol[j] = beta[col];
    }
    #pragma unroll
    for (int i = 0; i < 4; i++) {
        #pragma unroll
        for (int r = 0; r < 4; r++) {
            float s = 0.f, ss = 0.f;
            #pragma unroll
            for (int j = 0; j < 4; j++) {
                float v = acc[i][j][r] + bcol[j];
                s += v; ss += v * v;
            }
            #pragma unroll
            for (int o = 1; o <= 8; o <<= 1) {
                s  += __shfl_xor(s, o, 64);
                ss += __shfl_xor(ss, o, 64);
            }
            if (l15 == 0) {
                int row = wm0 + i * 16 + lq * 4 + r;
                red_s[wn_idx][row] = s;
                red_ss[wn_idx][row] = ss;
            }
        }
    }
    __syncthreads();
    #pragma unroll
    for (int i = 0; i < 4; i++) {
        #pragma unroll
        for (int r = 0; r < 4; r++) {
            int lrow = wm0 + i * 16 + lq * 4 + r;
            int row = bm + lrow;
            if (row < M) {
                float S  = red_s[0][lrow] + red_s[1][lrow] + red_s[2][lrow] + red_s[3][lrow];
                float SS = red_ss[0][lrow] + red_ss[1][lrow] + red_ss[2][lrow] + red_ss[3][lrow];
                float mn = S * (1.f / H_DIM);
                float var = SS * (1.f / H_DIM) - mn * mn;
                float rstd = rsqrtf(var + 1e-5f);
                #pragma unroll
                for (int j = 0; j < 4; j++) {
                    int col = wn0 + j * 16 + l15;
                    float v = acc[i][j][r] + bcol[j];
                    float o = fmaxf((v - mn) * rstd * gcol[j] + becol[j], 0.f);
                    C[(size_t)row * H_DIM + col] = f2b(o);
                }
            }
        }
    }
}

// -------- XCC-pinned slice gather (fp8 input, bf16 output, self-loop fused) --------
// NS slices of 64 features (3.2 MB each -> fits one XCD's 4 MB L2). A block reads
// its REAL XCD id via s_getreg(HW_REG_XCC_ID) and claims a 64-node unit from the
// queue of slice (xcc & (NS-1)); steals from other queues when its own is drained
// (correctness never depends on the XCD mapping). Lane layout: r=lane>>2 edge
// slot (16 edges in flight), p=lane&3 16B chunk of the 64B slice row.

template<int F, int NS>
__global__ __launch_bounds__(256) void gather_slice_f8(const unsigned char* __restrict__ xw,
                                                       unsigned short* __restrict__ out,
                                                       const int* __restrict__ rowptr,
                                                       const int* __restrict__ csr_src,
                                                       const float* __restrict__ dinv,
                                                       int* __restrict__ qcnt, int n) {
    constexpr int UNIT = 64;
    const int units = (n + UNIT - 1) / UNIT;
    __shared__ int s_unit, s_q;
    if (threadIdx.x == 0) {
        int xcc = (int)__builtin_amdgcn_s_getreg(6164) & (NS - 1);  // hwreg(XCC_ID=20,0,4)
        int unit = -1, qsel = 0;
        #pragma unroll
        for (int a = 0; a < NS; a++) {
            int qq = (xcc + a) & (NS - 1);
            int i = atomicAdd(&qcnt[qq], 1);
            if (i < units) { unit = i; qsel = qq; break; }
        }
        s_unit = unit; s_q = qsel;
    }
    __syncthreads();
    int unit = s_unit, q = s_q;
    if (unit < 0) return;

    int wave = threadIdx.x >> 6, lane = threadIdx.x & 63;
    int r = lane >> 2;
    int p = lane & 3;
    const unsigned char* xws = xw + q * 64 + p * 16;
    int node0 = unit * UNIT + wave * (UNIT / 4);
    int node1 = min(node0 + UNIT / 4, n);

    for (int node = node0; node < node1; node++) {
        int beg = rowptr[node], end = rowptr[node + 1];
        float acc[16];
        #pragma unroll
        for (int k = 0; k < 16; k++) acc[k] = 0.f;
        for (int base = beg; base < end; base += 64) {
            int m = end - base; if (m > 64) m = 64;
            int s_reg = 0; float w_reg = 0.f;
            if (lane < m) { s_reg = csr_src[base + lane]; w_reg = dinv[s_reg]; }
            int groups = (m + 15) >> 4;
            for (int j = 0; j < groups; j++) {
                int e = j * 16 + r;
                int   se = __shfl(s_reg, e, 64);
                float we = __shfl(w_reg, e, 64);
                uint4 v = *(const uint4*)(xws + (size_t)se * F);
                accf8x16(acc, v, we);
            }
        }
        #pragma unroll
        for (int k = 0; k < 16; k++) {
            acc[k] += __shfl_xor(acc[k], 4, 64);
            acc[k] += __shfl_xor(acc[k], 8, 64);
            acc[k] += __shfl_xor(acc[k], 16, 64);
            acc[k] += __shfl_xor(acc[k], 32, 64);
        }
        if (r == 0) {
            float d = dinv[node];
            uint4 vo = *(const uint4*)(xw + (size_t)node * F + q * 64 + p * 16);
            float sv[16];
            decf8x16(sv, vo);
            float v[16];
            #pragma unroll
            for (int k = 0; k < 16; k++) v[k] = d * (acc[k] + d * sv[k]);
            uint4 o0, o1;
            o0.x = (unsigned int)f2b(v[0])  | ((unsigned int)f2b(v[1])  << 16);
            o0.y = (unsigned int)f2b(v[2])  | ((unsigned int)f2b(v[3])  << 16);
            o0.z = (unsigned int)f2b(v[4])  | ((unsigned int)f2b(v[5])  << 16);
            o0.w = (unsigned int)f2b(v[6])  | ((unsigned int)f2b(v[7])  << 16);
            o1.x = (unsigned int)f2b(v[8])  | ((unsigned int)f2b(v[9])  << 16);
            o1.y = (unsigned int)f2b(v[10]) | ((unsigned int)f2b(v[11]) << 16);
            o1.z = (unsigned int)f2b(v[12]) | ((unsigned int)f2b(v[13]) << 16);
            o1.w = (unsigned int)f2b(v[14]) | ((unsigned int)f2b(v[15]) << 16);
            *(uint4*)(out + (size_t)node * F + q * 64 + p * 16) = o0;
            *(uint4*)(out + (size_t)node * F + q * 64 + p * 16 + 8) = o1;
        }
    }
}

// -------- bias + LayerNorm + ReLU (wave-per-node), agg(bf16) -> h(bf16) --------

__global__ __launch_bounds__(256) void ln_relu(const ushort4* __restrict__ agg4,
                                               ushort4* __restrict__ out4,
                                               const float* __restrict__ bias,
                                               const float* __restrict__ gamma,
                                               const float* __restrict__ beta, int n) {
    int wave = threadIdx.x >> 6, lane = threadIdx.x & 63;
    int node = blockIdx.x * 4 + wave;
    if (node >= n) return;
    ushort4 a = agg4[(size_t)node * 64 + lane];
    float4 bi = *(const float4*)&bias[lane * 4];
    float v0 = b2f(a.x) + bi.x;
    float v1 = b2f(a.y) + bi.y;
    float v2 = b2f(a.z) + bi.z;
    float v3 = b2f(a.w) + bi.w;

    float s  = v0 + v1 + v2 + v3;
    float ss = v0 * v0 + v1 * v1 + v2 * v2 + v3 * v3;
    #pragma unroll
    for (int o = 1; o < 64; o <<= 1) {
        s  += __shfl_xor(s, o, 64);
        ss += __shfl_xor(ss, o, 64);
    }
    float mn = s * (1.f / H_DIM);
    float var = ss * (1.f / H_DIM) - mn * mn;
    float r = rsqrtf(var + 1e-5f);

    float4 ga = *(const float4*)&gamma[lane * 4];
    float4 be = *(const float4*)&beta[lane * 4];
    ushort4 o;
    o.x = f2b(fmaxf((v0 - mn) * r * ga.x + be.x, 0.f));
    o.y = f2b(fmaxf((v1 - mn) * r * ga.y + be.y, 0.f));
    o.z = f2b(fmaxf((v2 - mn) * r * ga.z + be.z, 0.f));
    o.w = f2b(fmaxf((v3 - mn) * r * ga.w + be.w, 0.f));
    out4[(size_t)node * 64 + lane] = o;
}

// ---------------- pooling ----------------

__global__ __launch_bounds__(256) void pool_kernel(const __hip_bfloat16* __restrict__ h,
                                                   const int* __restrict__ batch,
                                                   float* __restrict__ pooled, int n) {
    int t = threadIdx.x;
    int start = blockIdx.x * 64;
    int end = min(start + 64, n);
    if (start >= n) return;
    int cur = batch[start];
    float acc = 0.f;
    for (int i = start; i < end; ++i) {
        int g = batch[i];
        if (g != cur) {
            atomicAdd(&pooled[(size_t)cur * H_DIM + t], acc);
            acc = 0.f;
            cur = g;
        }
        acc += __bfloat162float(h[(size_t)i * H_DIM + t]);
    }
    atomicAdd(&pooled[(size_t)cur * H_DIM + t], acc);
}

// ---------------- FC head ----------------

__global__ __launch_bounds__(256) void fc_kernel(const float* __restrict__ pooled,
                                                 const int* __restrict__ gstart,
                                                 const float* __restrict__ gattr,
                                                 const float* __restrict__ fcW1,
                                                 const float* __restrict__ fcb1,
                                                 const float* __restrict__ fcW2,
                                                 const float* __restrict__ fcb2,
                                                 float* __restrict__ out) {
    __shared__ float zc[H_DIM + A_DIM];
    __shared__ float z1[H_DIM];
    int g = blockIdx.x, t = threadIdx.x;
    int c_i = gstart[g + 1] - gstart[g];
    float c = (float)(c_i > 1 ? c_i : 1);
    zc[t] = pooled[(size_t)g * H_DIM + t] / c;
    if (t < A_DIM) zc[H_DIM + t] = gattr[g * A_DIM + t];
    __syncthreads();
    float s = fcb1[t];
    for (int k = 0; k < H_DIM + A_DIM; k++)
        s += zc[k] * fcW1[(size_t)k * H_DIM + t];
    z1[t] = fmaxf(s, 0.f) * fcW2[t];
    __syncthreads();
    for (int off = 128; off; off >>= 1) {
        if (t < off) z1[t] += z1[t + off];
        __syncthreads();
    }
    if (t == 0) out[g] = z1[0] + fcb2[0];
}

// ---------------- launch ----------------

extern "C" void kernel_launch(void* const* d_in, const int* in_sizes, int n_in,
                              void* d_out, int out_size, void* d_ws, size_t ws_size,
                              hipStream_t stream) {
    const float* x     = (const float*)d_in[0];
    const float* gattr = (const float*)d_in[1];
    const int*   ei    = (const int*)d_in[2];
    const int*   batch = (const int*)d_in[3];
    const float* W1 = (const float*)d_in[4];  const float* b1 = (const float*)d_in[5];
    const float* W2 = (const float*)d_in[6];  const float* b2 = (const float*)d_in[7];
    const float* W3 = (const float*)d_in[8];  const float* b3 = (const float*)d_in[9];
    const float* g1 = (const float*)d_in[10]; const float* be1 = (const float*)d_in[11];
    const float* g2 = (const float*)d_in[12]; const float* be2 = (const float*)d_in[13];
    const float* g3 = (const float*)d_in[14]; const float* be3 = (const float*)d_in[15];
    const float* fcW1 = (const float*)d_in[16]; const float* fcb1 = (const float*)d_in[17];
    const float* fcW2 = (const float*)d_in[18]; const float* fcb2 = (const float*)d_in[19];
    float* out = (float*)d_out;

    char* w = (char*)d_ws;
    unsigned char*  Pb8 = (unsigned char*)w;  w += (size_t)N_NODES * H_DIM;       // xw fp8
    unsigned short* Hb  = (unsigned short*)w; w += (size_t)N_NODES * H_DIM * 2;   // h bf16
    unsigned short* Ab  = (unsigned short*)w; w += (size_t)N_NODES * H_DIM * 2;   // agg bf16
    unsigned char*  Xb8 = (unsigned char*)w;  w += (size_t)N_NODES * F_IN;        // x fp8
    unsigned short* AXb = (unsigned short*)w; w += (size_t)N_NODES * F_IN * 2;    // A·x bf16
    unsigned short* Wt1 = (unsigned short*)w; w += (size_t)H_DIM * F_IN * 2;
    unsigned short* Wt2 = (unsigned short*)w; w += (size_t)H_DIM * H_DIM * 2;
    unsigned short* Wt3 = (unsigned short*)w; w += (size_t)H_DIM * H_DIM * 2;
    float* dinv   = (float*)w; w += (size_t)N_NODES * 4;
    float* pooled = (float*)w; w += (size_t)G_NUM * H_DIM * 4;
    int* indeg    = (int*)w;   w += (size_t)N_NODES * 4;
    int* qcnt     = (int*)w;   w += (size_t)12 * 4;       // 3 gather queues x 4 slices
    int* rowptr   = (int*)w;   w += (size_t)(N_NODES + 1) * 4;
    int* pos      = (int*)w;   w += (size_t)N_NODES * 4;
    int* csr_src  = (int*)w;   w += (size_t)N_EDGES * 4;
    int* gstart   = (int*)w;   w += (size_t)(G_NUM + 1) * 4;
    int* bsum     = (int*)w;   w += (size_t)256 * 4;

    const int* srcp = ei;
    const int* dstp = ei + N_EDGES;
    const int n_sblk = (N_NODES + 255) / 256;   // 196
    const int units = (N_NODES + 63) / 64;      // 782

    // ---- CSR build (memset covers indeg + the 12 queue counters) ----
    hipMemsetAsync(indeg, 0, (size_t)N_NODES * sizeof(int) + 12 * sizeof(int), stream);
    indeg_kernel<<<(N_EDGES + 255) / 256, 256, 0, stream>>>(dstp, indeg, N_EDGES);
    scan1_kernel<<<n_sblk, 256, 0, stream>>>(indeg, rowptr, bsum, dinv, N_NODES);
    scan2_kernel<<<1, 256, 0, stream>>>(bsum, n_sblk, batch, gstart, pooled);
    scan3_kernel<<<n_sblk, 256, 0, stream>>>(rowptr, bsum, pos, N_NODES);
    place_kernel<<<(N_EDGES + 255) / 256, 256, 0, stream>>>(srcp, dstp, pos, csr_src, N_EDGES);

    // ---- conversions ----
    {
        int tot = N_NODES * F_IN / 4 + F_IN * H_DIM + 2 * H_DIM * H_DIM;
        conv_fused<<<(tot + 255) / 256, 256, 0, stream>>>((const float4*)x, (unsigned int*)Xb8,
                                                          W1, Wt1, W2, Wt2, W3, Wt3);
    }

    int gemm_blocks = (N_NODES + 127) / 128;
    int ln_blocks = (N_NODES + 3) / 4;

    // ---- layer 1: (A·X)·W1 with fused bias+LN+ReLU epilogue ----
    gather_slice_f8<F_IN, 2><<<2 * units, 256, 0, stream>>>(Xb8, AXb, rowptr, csr_src, dinv,
                                                            qcnt, N_NODES);
    gemm_ln<<<gemm_blocks, 512, 0, stream>>>(AXb, Wt1, Hb, b1, g1, be1, N_NODES, F_IN);

    // ---- layer 2 ----
    gemm_f8<<<gemm_blocks, 512, 0, stream>>>(Hb, Wt2, Pb8, N_NODES, H_DIM);
    gather_slice_f8<H_DIM, 4><<<4 * units, 256, 0, stream>>>(Pb8, Ab, rowptr, csr_src, dinv,
                                                             qcnt + 4, N_NODES);
    ln_relu<<<ln_blocks, 256, 0, stream>>>((const ushort4*)Ab, (ushort4*)Hb, b2, g2, be2, N_NODES);

    // ---- layer 3 ----
    gemm_f8<<<gemm_blocks, 512, 0, stream>>>(Hb, Wt3, Pb8, N_NODES, H_DIM);
    gather_slice_f8<H_DIM, 4><<<4 * units, 256, 0, stream>>>(Pb8, Ab, rowptr, csr_src, dinv,
                                                             qcnt + 8, N_NODES);
    ln_relu<<<ln_blocks, 256, 0, stream>>>((const ushort4*)Ab, (ushort4*)Hb, b3, g3, be3, N_NODES);

    // ---- pool + FC head ----
    pool_kernel<<<(N_NODES + 63) / 64, 256, 0, stream>>>((const __hip_bfloat16*)Hb, batch, pooled, N_NODES);
    fc_kernel<<<G_NUM, 256, 0, stream>>>(pooled, gstart, gattr, fcW1, fcb1, fcW2, fcb2, out);
}

// Round 10
// 428.081 us; speedup vs baseline: 1.8252x; 1.8252x over previous
//
#include <hip/hip_runtime.h>
#include <hip/hip_bf16.h>

#define N_NODES 50000
#define N_EDGES 800000
#define F_IN    128
#define H_DIM   256
#define G_NUM   64
#define A_DIM   8

typedef __attribute__((ext_vector_type(8))) short short8v;
typedef __attribute__((ext_vector_type(4))) float float4v;
typedef __attribute__((ext_vector_type(2))) float float2v;

__device__ __forceinline__ float b2f(unsigned short u) {
    return __uint_as_float(((unsigned int)u) << 16);
}
__device__ __forceinline__ unsigned short f2b(float v) {
    return __hip_bfloat16_raw(__float2bfloat16(v)).x;
}
__device__ __forceinline__ unsigned char f2fp8(float v) {
    return (unsigned char)(__builtin_amdgcn_cvt_pk_fp8_f32(v, v, 0, false) & 0xff);
}
__device__ __forceinline__ void accf8x4(float* a, unsigned int u, float w) {
    float2v lo = __builtin_amdgcn_cvt_pk_f32_fp8((int)u, false);
    float2v hi = __builtin_amdgcn_cvt_pk_f32_fp8((int)u, true);
    a[0] = fmaf(w, lo.x, a[0]); a[1] = fmaf(w, lo.y, a[1]);
    a[2] = fmaf(w, hi.x, a[2]); a[3] = fmaf(w, hi.y, a[3]);
}
__device__ __forceinline__ void accf8x16(float* a, uint4 v, float w) {
    accf8x4(a + 0, v.x, w); accf8x4(a + 4, v.y, w);
    accf8x4(a + 8, v.z, w); accf8x4(a + 12, v.w, w);
}
__device__ __forceinline__ void decf8x16(float* s, uint4 v) {
    float2v t;
    t = __builtin_amdgcn_cvt_pk_f32_fp8((int)v.x, false); s[0] = t.x; s[1] = t.y;
    t = __builtin_amdgcn_cvt_pk_f32_fp8((int)v.x, true);  s[2] = t.x; s[3] = t.y;
    t = __builtin_amdgcn_cvt_pk_f32_fp8((int)v.y, false); s[4] = t.x; s[5] = t.y;
    t = __builtin_amdgcn_cvt_pk_f32_fp8((int)v.y, true);  s[6] = t.x; s[7] = t.y;
    t = __builtin_amdgcn_cvt_pk_f32_fp8((int)v.z, false); s[8] = t.x; s[9] = t.y;
    t = __builtin_amdgcn_cvt_pk_f32_fp8((int)v.z, true);  s[10] = t.x; s[11] = t.y;
    t = __builtin_amdgcn_cvt_pk_f32_fp8((int)v.w, false); s[12] = t.x; s[13] = t.y;
    t = __builtin_amdgcn_cvt_pk_f32_fp8((int)v.w, true);  s[14] = t.x; s[15] = t.y;
}

// ---------------- CSR build ----------------

__global__ void indeg_kernel(const int* __restrict__ dst, int* __restrict__ indeg, int e) {
    int i = blockIdx.x * blockDim.x + threadIdx.x;
    if (i < e) atomicAdd(&indeg[dst[i]], 1);
}

__global__ __launch_bounds__(256) void scan1_kernel(const int* __restrict__ in,
                                                    int* __restrict__ out,
                                                    int* __restrict__ bsum,
                                                    float* __restrict__ dinv, int n) {
    __shared__ int tile[256];
    int b = blockIdx.x, t = threadIdx.x, i = b * 256 + t;
    int v = (i < n) ? in[i] : 0;
    if (i < n) dinv[i] = rsqrtf((float)v + 1.0f);
    tile[t] = v;
    __syncthreads();
    #pragma unroll
    for (int o = 1; o < 256; o <<= 1) {
        int add = (t >= o) ? tile[t - o] : 0;
        __syncthreads();
        tile[t] += add;
        __syncthreads();
    }
    if (i < n) out[i] = tile[t] - v;
    if (t == 255) bsum[b] = tile[255];
}

__global__ __launch_bounds__(256) void scan2_kernel(int* __restrict__ bsum, int nb,
                                                    const int* __restrict__ batch,
                                                    int* __restrict__ gstart,
                                                    float* __restrict__ pooled) {
    __shared__ int tile[256];
    int t = threadIdx.x;
    int v = (t < nb) ? bsum[t] : 0;
    tile[t] = v;
    __syncthreads();
    #pragma unroll
    for (int o = 1; o < 256; o <<= 1) {
        int add = (t >= o) ? tile[t - o] : 0;
        __syncthreads();
        tile[t] += add;
        __syncthreads();
    }
    if (t < nb) bsum[t] = tile[t] - v;
    if (t <= G_NUM) {
        int lo = 0, hi = N_NODES;
        while (lo < hi) {
            int mid = (lo + hi) >> 1;
            if (batch[mid] < t) lo = mid + 1; else hi = mid;
        }
        gstart[t] = lo;
    }
    for (int i = t; i < G_NUM * H_DIM; i += 256) pooled[i] = 0.f;
}

__global__ __launch_bounds__(256) void scan3_kernel(int* __restrict__ out,
                                                    const int* __restrict__ bsum,
                                                    int* __restrict__ pos, int n) {
    int i = blockIdx.x * blockDim.x + threadIdx.x;
    if (i < n) {
        int r = out[i] + bsum[i >> 8];
        out[i] = r;
        pos[i] = r;
    }
    if (i == 0) out[n] = N_EDGES;
}

// csr_src as ushort: N_NODES < 65536. Halves the random-scatter footprint
// (3.2 -> 1.6 MB) so lines survive in L2 between the ~32 writes each receives.
__global__ void place_kernel(const int* __restrict__ src, const int* __restrict__ dst,
                             int* __restrict__ pos, unsigned short* __restrict__ csr_src, int e) {
    int i = blockIdx.x * blockDim.x + threadIdx.x;
    if (i < e) {
        int s = src[i], d = dst[i];
        int slot = atomicAdd(&pos[d], 1);
        csr_src[slot] = (unsigned short)s;
    }
}

// ------- conversions: x -> fp8, W1/W2/W3 -> bf16 transposed -------

__global__ void conv_fused(const float4* __restrict__ x, unsigned int* __restrict__ xb8,
                           const float* __restrict__ W1, unsigned short* __restrict__ Wt1,
                           const float* __restrict__ W2, unsigned short* __restrict__ Wt2,
                           const float* __restrict__ W3, unsigned short* __restrict__ Wt3) {
    const int n_x  = N_NODES * F_IN / 4;
    const int n_w1 = F_IN * H_DIM;
    const int n_w2 = H_DIM * H_DIM;
    int i = blockIdx.x * blockDim.x + threadIdx.x;
    if (i < n_x) {
        float4 v = x[i];
        unsigned int pk = (unsigned int)__builtin_amdgcn_cvt_pk_fp8_f32(v.x, v.y, 0, false);
        pk = (unsigned int)__builtin_amdgcn_cvt_pk_fp8_f32(v.z, v.w, (int)pk, true);
        xb8[i] = pk;
    } else if (i < n_x + n_w1) {
        int j = i - n_x;
        int k = j / H_DIM, n = j % H_DIM;
        Wt1[(size_t)n * F_IN + k] = f2b(W1[j]);
    } else if (i < n_x + n_w1 + n_w2) {
        int j = i - n_x - n_w1;
        int k = j / H_DIM, n = j % H_DIM;
        Wt2[(size_t)n * H_DIM + k] = f2b(W2[j]);
    } else if (i < n_x + n_w1 + 2 * n_w2) {
        int j = i - n_x - n_w1 - n_w2;
        int k = j / H_DIM, n = j % H_DIM;
        Wt3[(size_t)n * H_DIM + k] = f2b(W3[j]);
    }
}

// ------- bf16 MFMA GEMM, BN=256, fp8 output -------

#define SK 40

__global__ __launch_bounds__(512) void gemm_f8(const unsigned short* __restrict__ A,
                                               const unsigned short* __restrict__ Bt,
                                               unsigned char* __restrict__ C8,
                                               int M, int K) {
    __shared__ unsigned short As[128][SK];
    __shared__ unsigned short Bs[256][SK];
    int t = threadIdx.x;
    int wave = t >> 6, lane = t & 63;
    int wm0 = (wave & 1) * 64, wn0 = (wave >> 1) * 64;
    int bm = blockIdx.x * 128;
    int l15 = lane & 15, lq = lane >> 4;
    float4v acc[4][4];
    #pragma unroll
    for (int i = 0; i < 4; i++)
        #pragma unroll
        for (int j = 0; j < 4; j++)
            acc[i][j] = (float4v){0.f, 0.f, 0.f, 0.f};

    for (int k0 = 0; k0 < K; k0 += 32) {
        {
            int row = t >> 2, koff = (t & 3) * 8;
            uint4 va = make_uint4(0u, 0u, 0u, 0u);
            if (bm + row < M)
                va = *(const uint4*)(A + (size_t)(bm + row) * K + k0 + koff);
            *(uint4*)&As[row][koff] = va;
        }
        #pragma unroll
        for (int h = 0; h < 2; h++) {
            int c = t + h * 512;
            int row = c >> 2, koff = (c & 3) * 8;
            uint4 vb = *(const uint4*)(Bt + (size_t)row * K + k0 + koff);
            *(uint4*)&Bs[row][koff] = vb;
        }
        __syncthreads();
        short8v af[4], bf[4];
        #pragma unroll
        for (int i = 0; i < 4; i++) {
            af[i] = *(const short8v*)&As[wm0 + i * 16 + l15][lq * 8];
            bf[i] = *(const short8v*)&Bs[wn0 + i * 16 + l15][lq * 8];
        }
        #pragma unroll
        for (int i = 0; i < 4; i++)
            #pragma unroll
            for (int j = 0; j < 4; j++)
                acc[i][j] = __builtin_amdgcn_mfma_f32_16x16x32_bf16(af[i], bf[j], acc[i][j], 0, 0, 0);
        __syncthreads();
    }
    #pragma unroll
    for (int i = 0; i < 4; i++) {
        #pragma unroll
        for (int r = 0; r < 4; r++) {
            int row = bm + wm0 + i * 16 + lq * 4 + r;
            if (row < M) {
                #pragma unroll
                for (int j = 0; j < 4; j++) {
                    int col = wn0 + j * 16 + l15;
                    C8[(size_t)row * H_DIM + col] = f2fp8(acc[i][j][r]);
                }
            }
        }
    }
}

// ------- GEMM1 with fused bias+LayerNorm+ReLU epilogue, bf16 output -------

__global__ __launch_bounds__(512) void gemm_ln(const unsigned short* __restrict__ A,
                                               const unsigned short* __restrict__ Bt,
                                               unsigned short* __restrict__ C,
                                               const float* __restrict__ bias,
                                               const float* __restrict__ gamma,
                                               const float* __restrict__ beta,
                                               int M, int K) {
    __shared__ unsigned short As[128][SK];
    __shared__ unsigned short Bs[256][SK];
    __shared__ float red_s[4][128];
    __shared__ float red_ss[4][128];
    int t = threadIdx.x;
    int wave = t >> 6, lane = t & 63;
    int wm0 = (wave & 1) * 64, wn0 = (wave >> 1) * 64;
    int wn_idx = wave >> 1;
    int bm = blockIdx.x * 128;
    int l15 = lane & 15, lq = lane >> 4;
    float4v acc[4][4];
    #pragma unroll
    for (int i = 0; i < 4; i++)
        #pragma unroll
        for (int j = 0; j < 4; j++)
            acc[i][j] = (float4v){0.f, 0.f, 0.f, 0.f};

    for (int k0 = 0; k0 < K; k0 += 32) {
        {
            int row = t >> 2, koff = (t & 3) * 8;
            uint4 va = make_uint4(0u, 0u, 0u, 0u);
            if (bm + row < M)
                va = *(const uint4*)(A + (size_t)(bm + row) * K + k0 + koff);
            *(uint4*)&As[row][koff] = va;
        }
        #pragma unroll
        for (int h = 0; h < 2; h++) {
            int c = t + h * 512;
            int row = c >> 2, koff = (c & 3) * 8;
            uint4 vb = *(const uint4*)(Bt + (size_t)row * K + k0 + koff);
            *(uint4*)&Bs[row][koff] = vb;
        }
        __syncthreads();
        short8v af[4], bf[4];
        #pragma unroll
        for (int i = 0; i < 4; i++) {
            af[i] = *(const short8v*)&As[wm0 + i * 16 + l15][lq * 8];
            bf[i] = *(const short8v*)&Bs[wn0 + i * 16 + l15][lq * 8];
        }
        #pragma unroll
        for (int i = 0; i < 4; i++)
            #pragma unroll
            for (int j = 0; j < 4; j++)
                acc[i][j] = __builtin_amdgcn_mfma_f32_16x16x32_bf16(af[i], bf[j], acc[i][j], 0, 0, 0);
        __syncthreads();
    }

    float bcol[4], gcol[4], becol[4];
    #pragma unroll
    for (int j = 0; j < 4; j++) {
        int col = wn0 + j * 16 + l15;
        bcol[j] = bias[col]; gcol[j] = gamma[col]; becol[j] = beta[col];
    }
    #pragma unroll
    for (int i = 0; i < 4; i++) {
        #pragma unroll
        for (int r = 0; r < 4; r++) {
            float s = 0.f, ss = 0.f;
            #pragma unroll
            for (int j = 0; j < 4; j++) {
                float v = acc[i][j][r] + bcol[j];
                s += v; ss += v * v;
            }
            #pragma unroll
            for (int o = 1; o <= 8; o <<= 1) {
                s  += __shfl_xor(s, o, 64);
                ss += __shfl_xor(ss, o, 64);
            }
            if (l15 == 0) {
                int row = wm0 + i * 16 + lq * 4 + r;
                red_s[wn_idx][row] = s;
                red_ss[wn_idx][row] = ss;
            }
        }
    }
    __syncthreads();
    #pragma unroll
    for (int i = 0; i < 4; i++) {
        #pragma unroll
        for (int r = 0; r < 4; r++) {
            int lrow = wm0 + i * 16 + lq * 4 + r;
            int row = bm + lrow;
            if (row < M) {
                float S  = red_s[0][lrow] + red_s[1][lrow] + red_s[2][lrow] + red_s[3][lrow];
                float SS = red_ss[0][lrow] + red_ss[1][lrow] + red_ss[2][lrow] + red_ss[3][lrow];
                float mn = S * (1.f / H_DIM);
                float var = SS * (1.f / H_DIM) - mn * mn;
                float rstd = rsqrtf(var + 1e-5f);
                #pragma unroll
                for (int j = 0; j < 4; j++) {
                    int col = wn0 + j * 16 + l15;
                    float v = acc[i][j][r] + bcol[j];
                    float o = fmaxf((v - mn) * rstd * gcol[j] + becol[j], 0.f);
                    C[(size_t)row * H_DIM + col] = f2b(o);
                }
            }
        }
    }
}

// -------- fp8 gather (wave-per-node, 16B lane = 16 fp8 features) --------

template<int F, bool DO_LN>
__global__ __launch_bounds__(256) void gather_f8(const unsigned char* __restrict__ xw,
                                                 unsigned short* __restrict__ out,
                                                 const int* __restrict__ rowptr,
                                                 const unsigned short* __restrict__ csr_src,
                                                 const float* __restrict__ dinv,
                                                 const float* __restrict__ bias,
                                                 const float* __restrict__ gamma,
                                                 const float* __restrict__ beta, int n) {
    constexpr int LPR = F / 16;     // lanes per row
    constexpr int G   = 64 / LPR;   // edges per load group
    int wave = threadIdx.x >> 6, lane = threadIdx.x & 63;
    int node = blockIdx.x * 4 + wave;
    if (node >= n) return;
    int r = lane / LPR;
    int p = lane % LPR;
    int beg = rowptr[node], end = rowptr[node + 1];
    const unsigned char* xwp = xw + (size_t)p * 16;
    float acc[16];
    #pragma unroll
    for (int k = 0; k < 16; k++) acc[k] = 0.f;

    for (int base = beg; base < end; base += 64) {
        int m = end - base; if (m > 64) m = 64;
        int s_reg = 0; float w_reg = 0.f;
        if (lane < m) { s_reg = (int)csr_src[base + lane]; w_reg = dinv[s_reg]; }
        int groups = (m + G - 1) / G;
        int j = 0;
        for (; j + 4 <= groups; j += 4) {
            int e0 = j * G + r, e1 = e0 + G, e2 = e0 + 2 * G, e3 = e0 + 3 * G;
            int   s0 = __shfl(s_reg, e0, 64), s1 = __shfl(s_reg, e1, 64);
            int   s2 = __shfl(s_reg, e2, 64), s3 = __shfl(s_reg, e3, 64);
            float w0 = __shfl(w_reg, e0, 64), w1 = __shfl(w_reg, e1, 64);
            float w2 = __shfl(w_reg, e2, 64), w3 = __shfl(w_reg, e3, 64);
            uint4 v0 = *(const uint4*)(xwp + (size_t)s0 * F);
            uint4 v1 = *(const uint4*)(xwp + (size_t)s1 * F);
            uint4 v2 = *(const uint4*)(xwp + (size_t)s2 * F);
            uint4 v3 = *(const uint4*)(xwp + (size_t)s3 * F);
            accf8x16(acc, v0, w0); accf8x16(acc, v1, w1);
            accf8x16(acc, v2, w2); accf8x16(acc, v3, w3);
        }
        for (; j < groups; j++) {
            int e0 = j * G + r;
            int   s0 = __shfl(s_reg, e0, 64);
            float w0 = __shfl(w_reg, e0, 64);
            uint4 v0 = *(const uint4*)(xwp + (size_t)s0 * F);
            accf8x16(acc, v0, w0);
        }
    }

    #pragma unroll
    for (int k = 0; k < 16; k++) {
        acc[k] += __shfl_xor(acc[k], 32, 64);
        if (LPR <= 16) acc[k] += __shfl_xor(acc[k], 16, 64);
        if (LPR <= 8)  acc[k] += __shfl_xor(acc[k], 8, 64);
    }

    float d = dinv[node];
    uint4 vo = *(const uint4*)(xw + (size_t)node * F + p * 16);
    float sv[16];
    decf8x16(sv, vo);
    float v[16];
    #pragma unroll
    for (int k = 0; k < 16; k++) v[k] = d * (acc[k] + d * sv[k]);

    if (DO_LN) {
        #pragma unroll
        for (int q = 0; q < 4; q++) {
            float4 bi = ((const float4*)bias)[p * 4 + q];
            v[q * 4 + 0] += bi.x; v[q * 4 + 1] += bi.y;
            v[q * 4 + 2] += bi.z; v[q * 4 + 3] += bi.w;
        }
        float s = 0.f, ss = 0.f;
        #pragma unroll
        for (int k = 0; k < 16; k++) { s += v[k]; ss += v[k] * v[k]; }
        #pragma unroll
        for (int o = 1; o < LPR; o <<= 1) {
            s  += __shfl_xor(s, o, 64);
            ss += __shfl_xor(ss, o, 64);
        }
        float mn = s * (1.f / F);
        float var = ss * (1.f / F) - mn * mn;
        float rstd = rsqrtf(var + 1e-5f);
        #pragma unroll
        for (int q = 0; q < 4; q++) {
            float4 ga = ((const float4*)gamma)[p * 4 + q];
            float4 be = ((const float4*)beta)[p * 4 + q];
            v[q * 4 + 0] = fmaxf((v[q * 4 + 0] - mn) * rstd * ga.x + be.x, 0.f);
            v[q * 4 + 1] = fmaxf((v[q * 4 + 1] - mn) * rstd * ga.y + be.y, 0.f);
            v[q * 4 + 2] = fmaxf((v[q * 4 + 2] - mn) * rstd * ga.z + be.z, 0.f);
            v[q * 4 + 3] = fmaxf((v[q * 4 + 3] - mn) * rstd * ga.w + be.w, 0.f);
        }
    }

    if (r == 0) {
        uint4 o0, o1;
        o0.x = (unsigned int)f2b(v[0])  | ((unsigned int)f2b(v[1])  << 16);
        o0.y = (unsigned int)f2b(v[2])  | ((unsigned int)f2b(v[3])  << 16);
        o0.z = (unsigned int)f2b(v[4])  | ((unsigned int)f2b(v[5])  << 16);
        o0.w = (unsigned int)f2b(v[6])  | ((unsigned int)f2b(v[7])  << 16);
        o1.x = (unsigned int)f2b(v[8])  | ((unsigned int)f2b(v[9])  << 16);
        o1.y = (unsigned int)f2b(v[10]) | ((unsigned int)f2b(v[11]) << 16);
        o1.z = (unsigned int)f2b(v[12]) | ((unsigned int)f2b(v[13]) << 16);
        o1.w = (unsigned int)f2b(v[14]) | ((unsigned int)f2b(v[15]) << 16);
        *(uint4*)(out + (size_t)node * F + p * 16) = o0;
        *(uint4*)(out + (size_t)node * F + p * 16 + 8) = o1;
    }
}

// ---------------- pooling ----------------

__global__ __launch_bounds__(256) void pool_kernel(const __hip_bfloat16* __restrict__ h,
                                                   const int* __restrict__ batch,
                                                   float* __restrict__ pooled, int n) {
    int t = threadIdx.x;
    int start = blockIdx.x * 64;
    int end = min(start + 64, n);
    if (start >= n) return;
    int cur = batch[start];
    float acc = 0.f;
    for (int i = start; i < end; ++i) {
        int g = batch[i];
        if (g != cur) {
            atomicAdd(&pooled[(size_t)cur * H_DIM + t], acc);
            acc = 0.f;
            cur = g;
        }
        acc += __bfloat162float(h[(size_t)i * H_DIM + t]);
    }
    atomicAdd(&pooled[(size_t)cur * H_DIM + t], acc);
}

// ---------------- FC head ----------------

__global__ __launch_bounds__(256) void fc_kernel(const float* __restrict__ pooled,
                                                 const int* __restrict__ gstart,
                                                 const float* __restrict__ gattr,
                                                 const float* __restrict__ fcW1,
                                                 const float* __restrict__ fcb1,
                                                 const float* __restrict__ fcW2,
                                                 const float* __restrict__ fcb2,
                                                 float* __restrict__ out) {
    __shared__ float zc[H_DIM + A_DIM];
    __shared__ float z1[H_DIM];
    int g = blockIdx.x, t = threadIdx.x;
    int c_i = gstart[g + 1] - gstart[g];
    float c = (float)(c_i > 1 ? c_i : 1);
    zc[t] = pooled[(size_t)g * H_DIM + t] / c;
    if (t < A_DIM) zc[H_DIM + t] = gattr[g * A_DIM + t];
    __syncthreads();
    float s = fcb1[t];
    for (int k = 0; k < H_DIM + A_DIM; k++)
        s += zc[k] * fcW1[(size_t)k * H_DIM + t];
    z1[t] = fmaxf(s, 0.f) * fcW2[t];
    __syncthreads();
    for (int off = 128; off; off >>= 1) {
        if (t < off) z1[t] += z1[t + off];
        __syncthreads();
    }
    if (t == 0) out[g] = z1[0] + fcb2[0];
}

// ---------------- launch ----------------

extern "C" void kernel_launch(void* const* d_in, const int* in_sizes, int n_in,
                              void* d_out, int out_size, void* d_ws, size_t ws_size,
                              hipStream_t stream) {
    const float* x     = (const float*)d_in[0];
    const float* gattr = (const float*)d_in[1];
    const int*   ei    = (const int*)d_in[2];
    const int*   batch = (const int*)d_in[3];
    const float* W1 = (const float*)d_in[4];  const float* b1 = (const float*)d_in[5];
    const float* W2 = (const float*)d_in[6];  const float* b2 = (const float*)d_in[7];
    const float* W3 = (const float*)d_in[8];  const float* b3 = (const float*)d_in[9];
    const float* g1 = (const float*)d_in[10]; const float* be1 = (const float*)d_in[11];
    const float* g2 = (const float*)d_in[12]; const float* be2 = (const float*)d_in[13];
    const float* g3 = (const float*)d_in[14]; const float* be3 = (const float*)d_in[15];
    const float* fcW1 = (const float*)d_in[16]; const float* fcb1 = (const float*)d_in[17];
    const float* fcW2 = (const float*)d_in[18]; const float* fcb2 = (const float*)d_in[19];
    float* out = (float*)d_out;

    char* w = (char*)d_ws;
    unsigned char*  Pb8 = (unsigned char*)w;  w += (size_t)N_NODES * H_DIM;       // xw fp8
    unsigned short* Hb  = (unsigned short*)w; w += (size_t)N_NODES * H_DIM * 2;   // h bf16
    unsigned char*  Xb8 = (unsigned char*)w;  w += (size_t)N_NODES * F_IN;        // x fp8
    unsigned short* AXb = (unsigned short*)w; w += (size_t)N_NODES * F_IN * 2;    // A·x bf16
    unsigned short* Wt1 = (unsigned short*)w; w += (size_t)H_DIM * F_IN * 2;
    unsigned short* Wt2 = (unsigned short*)w; w += (size_t)H_DIM * H_DIM * 2;
    unsigned short* Wt3 = (unsigned short*)w; w += (size_t)H_DIM * H_DIM * 2;
    float* dinv   = (float*)w; w += (size_t)N_NODES * 4;
    float* pooled = (float*)w; w += (size_t)G_NUM * H_DIM * 4;
    int* indeg    = (int*)w;   w += (size_t)N_NODES * 4;
    int* rowptr   = (int*)w;   w += (size_t)(N_NODES + 1) * 4;
    int* pos      = (int*)w;   w += (size_t)N_NODES * 4;
    unsigned short* csr_src = (unsigned short*)w; w += (size_t)N_EDGES * 2;
    int* gstart   = (int*)w;   w += (size_t)(G_NUM + 1) * 4;
    int* bsum     = (int*)w;   w += (size_t)256 * 4;

    const int* srcp = ei;
    const int* dstp = ei + N_EDGES;
    const int n_sblk = (N_NODES + 255) / 256;   // 196

    // ---- CSR build ----
    hipMemsetAsync(indeg, 0, (size_t)N_NODES * sizeof(int), stream);
    indeg_kernel<<<(N_EDGES + 255) / 256, 256, 0, stream>>>(dstp, indeg, N_EDGES);
    scan1_kernel<<<n_sblk, 256, 0, stream>>>(indeg, rowptr, bsum, dinv, N_NODES);
    scan2_kernel<<<1, 256, 0, stream>>>(bsum, n_sblk, batch, gstart, pooled);
    scan3_kernel<<<n_sblk, 256, 0, stream>>>(rowptr, bsum, pos, N_NODES);
    place_kernel<<<(N_EDGES + 255) / 256, 256, 0, stream>>>(srcp, dstp, pos, csr_src, N_EDGES);

    // ---- conversions ----
    {
        int tot = N_NODES * F_IN / 4 + F_IN * H_DIM + 2 * H_DIM * H_DIM;
        conv_fused<<<(tot + 255) / 256, 256, 0, stream>>>((const float4*)x, (unsigned int*)Xb8,
                                                          W1, Wt1, W2, Wt2, W3, Wt3);
    }

    int gemm_blocks = (N_NODES + 127) / 128;
    int gather_blocks = (N_NODES + 3) / 4;

    // ---- layer 1: (A·X)·W1 with fused bias+LN+ReLU epilogue ----
    gather_f8<F_IN, false><<<gather_blocks, 256, 0, stream>>>(Xb8, AXb, rowptr, csr_src, dinv,
                                                              nullptr, nullptr, nullptr, N_NODES);
    gemm_ln<<<gemm_blocks, 512, 0, stream>>>(AXb, Wt1, Hb, b1, g1, be1, N_NODES, F_IN);

    // ---- layer 2 ----
    gemm_f8<<<gemm_blocks, 512, 0, stream>>>(Hb, Wt2, Pb8, N_NODES, H_DIM);
    gather_f8<H_DIM, true><<<gather_blocks, 256, 0, stream>>>(Pb8, Hb, rowptr, csr_src, dinv,
                                                              b2, g2, be2, N_NODES);
    // ---- layer 3 ----
    gemm_f8<<<gemm_blocks, 512, 0, stream>>>(Hb, Wt3, Pb8, N_NODES, H_DIM);
    gather_f8<H_DIM, true><<<gather_blocks, 256, 0, stream>>>(Pb8, Hb, rowptr, csr_src, dinv,
                                                              b3, g3, be3, N_NODES);

    // ---- pool + FC head ----
    pool_kernel<<<(N_NODES + 63) / 64, 256, 0, stream>>>((const __hip_bfloat16*)Hb, batch, pooled, N_NODES);
    fc_kernel<<<G_NUM, 256, 0, stream>>>(pooled, gstart, gattr, fcW1, fcb1, fcW2, fcb2, out);
}

// Round 11
// 416.848 us; speedup vs baseline: 1.8744x; 1.0269x over previous
//
#include <hip/hip_runtime.h>
#include <hip/hip_bf16.h>

#define N_NODES 50000
#define N_EDGES 800000
#define F_IN    128
#define H_DIM   256
#define G_NUM   64
#define A_DIM   8

typedef __attribute__((ext_vector_type(8))) short short8v;
typedef __attribute__((ext_vector_type(4))) float float4v;
typedef __attribute__((ext_vector_type(2))) float float2v;

__device__ __forceinline__ float b2f(unsigned short u) {
    return __uint_as_float(((unsigned int)u) << 16);
}
__device__ __forceinline__ unsigned short f2b(float v) {
    return __hip_bfloat16_raw(__float2bfloat16(v)).x;
}
__device__ __forceinline__ unsigned char f2fp8(float v) {
    return (unsigned char)(__builtin_amdgcn_cvt_pk_fp8_f32(v, v, 0, false) & 0xff);
}
// packed accumulate: 16 fp8 -> 8 float2 pk-fma (v_pk_fma_f32 path)
__device__ __forceinline__ void accp16(float2v* a, uint4 v, float w) {
    float2v w2 = {w, w};
    a[0] = __builtin_amdgcn_cvt_pk_f32_fp8((int)v.x, false) * w2 + a[0];
    a[1] = __builtin_amdgcn_cvt_pk_f32_fp8((int)v.x, true)  * w2 + a[1];
    a[2] = __builtin_amdgcn_cvt_pk_f32_fp8((int)v.y, false) * w2 + a[2];
    a[3] = __builtin_amdgcn_cvt_pk_f32_fp8((int)v.y, true)  * w2 + a[3];
    a[4] = __builtin_amdgcn_cvt_pk_f32_fp8((int)v.z, false) * w2 + a[4];
    a[5] = __builtin_amdgcn_cvt_pk_f32_fp8((int)v.z, true)  * w2 + a[5];
    a[6] = __builtin_amdgcn_cvt_pk_f32_fp8((int)v.w, false) * w2 + a[6];
    a[7] = __builtin_amdgcn_cvt_pk_f32_fp8((int)v.w, true)  * w2 + a[7];
}
__device__ __forceinline__ void decf8x16(float* s, uint4 v) {
    float2v t;
    t = __builtin_amdgcn_cvt_pk_f32_fp8((int)v.x, false); s[0] = t.x; s[1] = t.y;
    t = __builtin_amdgcn_cvt_pk_f32_fp8((int)v.x, true);  s[2] = t.x; s[3] = t.y;
    t = __builtin_amdgcn_cvt_pk_f32_fp8((int)v.y, false); s[4] = t.x; s[5] = t.y;
    t = __builtin_amdgcn_cvt_pk_f32_fp8((int)v.y, true);  s[6] = t.x; s[7] = t.y;
    t = __builtin_amdgcn_cvt_pk_f32_fp8((int)v.z, false); s[8] = t.x; s[9] = t.y;
    t = __builtin_amdgcn_cvt_pk_f32_fp8((int)v.z, true);  s[10] = t.x; s[11] = t.y;
    t = __builtin_amdgcn_cvt_pk_f32_fp8((int)v.w, false); s[12] = t.x; s[13] = t.y;
    t = __builtin_amdgcn_cvt_pk_f32_fp8((int)v.w, true);  s[14] = t.x; s[15] = t.y;
}

// -------- merged init: indeg atomics (blocks [0,EB)) + conversions (rest) --------
// indeg is atomic-latency-bound, conv is BW-bound -> co-resident overlap.

__global__ void init_kernel(const int* __restrict__ dst, int* __restrict__ indeg,
                            const float4* __restrict__ x, unsigned int* __restrict__ xb8,
                            const float* __restrict__ W1, unsigned short* __restrict__ Wt1,
                            const float* __restrict__ W2, unsigned short* __restrict__ Wt2,
                            const float* __restrict__ W3, unsigned short* __restrict__ Wt3) {
    const int EB = (N_EDGES + 255) / 256;
    const int n_x  = N_NODES * F_IN / 4;
    const int n_w1 = F_IN * H_DIM;
    const int n_w2 = H_DIM * H_DIM;
    int b = blockIdx.x, t = threadIdx.x;
    if (b < EB) {
        int i = b * 256 + t;
        if (i < N_EDGES) atomicAdd(&indeg[dst[i]], 1);
        return;
    }
    int i = (b - EB) * 256 + t;
    if (i < n_x) {
        float4 v = x[i];
        unsigned int pk = (unsigned int)__builtin_amdgcn_cvt_pk_fp8_f32(v.x, v.y, 0, false);
        pk = (unsigned int)__builtin_amdgcn_cvt_pk_fp8_f32(v.z, v.w, (int)pk, true);
        xb8[i] = pk;
    } else if (i < n_x + n_w1) {
        int j = i - n_x;
        int k = j / H_DIM, n = j % H_DIM;
        Wt1[(size_t)n * F_IN + k] = f2b(W1[j]);
    } else if (i < n_x + n_w1 + n_w2) {
        int j = i - n_x - n_w1;
        int k = j / H_DIM, n = j % H_DIM;
        Wt2[(size_t)n * H_DIM + k] = f2b(W2[j]);
    } else if (i < n_x + n_w1 + 2 * n_w2) {
        int j = i - n_x - n_w1 - n_w2;
        int k = j / H_DIM, n = j % H_DIM;
        Wt3[(size_t)n * H_DIM + k] = f2b(W3[j]);
    }
}

// ---------------- CSR build ----------------

__global__ __launch_bounds__(256) void scan1_kernel(const int* __restrict__ in,
                                                    int* __restrict__ out,
                                                    int* __restrict__ bsum,
                                                    float* __restrict__ dinv, int n) {
    __shared__ int tile[256];
    int b = blockIdx.x, t = threadIdx.x, i = b * 256 + t;
    int v = (i < n) ? in[i] : 0;
    if (i < n) dinv[i] = rsqrtf((float)v + 1.0f);
    tile[t] = v;
    __syncthreads();
    #pragma unroll
    for (int o = 1; o < 256; o <<= 1) {
        int add = (t >= o) ? tile[t - o] : 0;
        __syncthreads();
        tile[t] += add;
        __syncthreads();
    }
    if (i < n) out[i] = tile[t] - v;
    if (t == 255) bsum[b] = tile[255];
}

__global__ __launch_bounds__(256) void scan2_kernel(int* __restrict__ bsum, int nb,
                                                    const int* __restrict__ batch,
                                                    int* __restrict__ gstart,
                                                    float* __restrict__ pooled) {
    __shared__ int tile[256];
    int t = threadIdx.x;
    int v = (t < nb) ? bsum[t] : 0;
    tile[t] = v;
    __syncthreads();
    #pragma unroll
    for (int o = 1; o < 256; o <<= 1) {
        int add = (t >= o) ? tile[t - o] : 0;
        __syncthreads();
        tile[t] += add;
        __syncthreads();
    }
    if (t < nb) bsum[t] = tile[t] - v;
    if (t <= G_NUM) {
        int lo = 0, hi = N_NODES;
        while (lo < hi) {
            int mid = (lo + hi) >> 1;
            if (batch[mid] < t) lo = mid + 1; else hi = mid;
        }
        gstart[t] = lo;
    }
    for (int i = t; i < G_NUM * H_DIM; i += 256) pooled[i] = 0.f;
}

__global__ __launch_bounds__(256) void scan3_kernel(int* __restrict__ out,
                                                    const int* __restrict__ bsum,
                                                    int* __restrict__ pos, int n) {
    int i = blockIdx.x * blockDim.x + threadIdx.x;
    if (i < n) {
        int r = out[i] + bsum[i >> 8];
        out[i] = r;
        pos[i] = r;
    }
    if (i == 0) out[n] = N_EDGES;
}

// csr_src as ushort (N_NODES < 65536): 1.6 MB scatter footprint
__global__ void place_kernel(const int* __restrict__ src, const int* __restrict__ dst,
                             int* __restrict__ pos, unsigned short* __restrict__ csr_src, int e) {
    int i = blockIdx.x * blockDim.x + threadIdx.x;
    if (i < e) {
        int s = src[i], d = dst[i];
        int slot = atomicAdd(&pos[d], 1);
        csr_src[slot] = (unsigned short)s;
    }
}

// ------- bf16 MFMA GEMM, BN=256, fp8 output -------

#define SK 40

__global__ __launch_bounds__(512) void gemm_f8(const unsigned short* __restrict__ A,
                                               const unsigned short* __restrict__ Bt,
                                               unsigned char* __restrict__ C8,
                                               int M, int K) {
    __shared__ unsigned short As[128][SK];
    __shared__ unsigned short Bs[256][SK];
    int t = threadIdx.x;
    int wave = t >> 6, lane = t & 63;
    int wm0 = (wave & 1) * 64, wn0 = (wave >> 1) * 64;
    int bm = blockIdx.x * 128;
    int l15 = lane & 15, lq = lane >> 4;
    float4v acc[4][4];
    #pragma unroll
    for (int i = 0; i < 4; i++)
        #pragma unroll
        for (int j = 0; j < 4; j++)
            acc[i][j] = (float4v){0.f, 0.f, 0.f, 0.f};

    for (int k0 = 0; k0 < K; k0 += 32) {
        {
            int row = t >> 2, koff = (t & 3) * 8;
            uint4 va = make_uint4(0u, 0u, 0u, 0u);
            if (bm + row < M)
                va = *(const uint4*)(A + (size_t)(bm + row) * K + k0 + koff);
            *(uint4*)&As[row][koff] = va;
        }
        #pragma unroll
        for (int h = 0; h < 2; h++) {
            int c = t + h * 512;
            int row = c >> 2, koff = (c & 3) * 8;
            uint4 vb = *(const uint4*)(Bt + (size_t)row * K + k0 + koff);
            *(uint4*)&Bs[row][koff] = vb;
        }
        __syncthreads();
        short8v af[4], bf[4];
        #pragma unroll
        for (int i = 0; i < 4; i++) {
            af[i] = *(const short8v*)&As[wm0 + i * 16 + l15][lq * 8];
            bf[i] = *(const short8v*)&Bs[wn0 + i * 16 + l15][lq * 8];
        }
        #pragma unroll
        for (int i = 0; i < 4; i++)
            #pragma unroll
            for (int j = 0; j < 4; j++)
                acc[i][j] = __builtin_amdgcn_mfma_f32_16x16x32_bf16(af[i], bf[j], acc[i][j], 0, 0, 0);
        __syncthreads();
    }
    #pragma unroll
    for (int i = 0; i < 4; i++) {
        #pragma unroll
        for (int r = 0; r < 4; r++) {
            int row = bm + wm0 + i * 16 + lq * 4 + r;
            if (row < M) {
                #pragma unroll
                for (int j = 0; j < 4; j++) {
                    int col = wn0 + j * 16 + l15;
                    C8[(size_t)row * H_DIM + col] = f2fp8(acc[i][j][r]);
                }
            }
        }
    }
}

// ------- GEMM1 with fused bias+LayerNorm+ReLU epilogue, bf16 output -------

__global__ __launch_bounds__(512) void gemm_ln(const unsigned short* __restrict__ A,
                                               const unsigned short* __restrict__ Bt,
                                               unsigned short* __restrict__ C,
                                               const float* __restrict__ bias,
                                               const float* __restrict__ gamma,
                                               const float* __restrict__ beta,
                                               int M, int K) {
    __shared__ unsigned short As[128][SK];
    __shared__ unsigned short Bs[256][SK];
    __shared__ float red_s[4][128];
    __shared__ float red_ss[4][128];
    int t = threadIdx.x;
    int wave = t >> 6, lane = t & 63;
    int wm0 = (wave & 1) * 64, wn0 = (wave >> 1) * 64;
    int wn_idx = wave >> 1;
    int bm = blockIdx.x * 128;
    int l15 = lane & 15, lq = lane >> 4;
    float4v acc[4][4];
    #pragma unroll
    for (int i = 0; i < 4; i++)
        #pragma unroll
        for (int j = 0; j < 4; j++)
            acc[i][j] = (float4v){0.f, 0.f, 0.f, 0.f};

    for (int k0 = 0; k0 < K; k0 += 32) {
        {
            int row = t >> 2, koff = (t & 3) * 8;
            uint4 va = make_uint4(0u, 0u, 0u, 0u);
            if (bm + row < M)
                va = *(const uint4*)(A + (size_t)(bm + row) * K + k0 + koff);
            *(uint4*)&As[row][koff] = va;
        }
        #pragma unroll
        for (int h = 0; h < 2; h++) {
            int c = t + h * 512;
            int row = c >> 2, koff = (c & 3) * 8;
            uint4 vb = *(const uint4*)(Bt + (size_t)row * K + k0 + koff);
            *(uint4*)&Bs[row][koff] = vb;
        }
        __syncthreads();
        short8v af[4], bf[4];
        #pragma unroll
        for (int i = 0; i < 4; i++) {
            af[i] = *(const short8v*)&As[wm0 + i * 16 + l15][lq * 8];
            bf[i] = *(const short8v*)&Bs[wn0 + i * 16 + l15][lq * 8];
        }
        #pragma unroll
        for (int i = 0; i < 4; i++)
            #pragma unroll
            for (int j = 0; j < 4; j++)
                acc[i][j] = __builtin_amdgcn_mfma_f32_16x16x32_bf16(af[i], bf[j], acc[i][j], 0, 0, 0);
        __syncthreads();
    }

    float bcol[4], gcol[4], becol[4];
    #pragma unroll
    for (int j = 0; j < 4; j++) {
        int col = wn0 + j * 16 + l15;
        bcol[j] = bias[col]; gcol[j] = gamma[col]; becol[j] = beta[col];
    }
    #pragma unroll
    for (int i = 0; i < 4; i++) {
        #pragma unroll
        for (int r = 0; r < 4; r++) {
            float s = 0.f, ss = 0.f;
            #pragma unroll
            for (int j = 0; j < 4; j++) {
                float v = acc[i][j][r] + bcol[j];
                s += v; ss += v * v;
            }
            #pragma unroll
            for (int o = 1; o <= 8; o <<= 1) {
                s  += __shfl_xor(s, o, 64);
                ss += __shfl_xor(ss, o, 64);
            }
            if (l15 == 0) {
                int row = wm0 + i * 16 + lq * 4 + r;
                red_s[wn_idx][row] = s;
                red_ss[wn_idx][row] = ss;
            }
        }
    }
    __syncthreads();
    #pragma unroll
    for (int i = 0; i < 4; i++) {
        #pragma unroll
        for (int r = 0; r < 4; r++) {
            int lrow = wm0 + i * 16 + lq * 4 + r;
            int row = bm + lrow;
            if (row < M) {
                float S  = red_s[0][lrow] + red_s[1][lrow] + red_s[2][lrow] + red_s[3][lrow];
                float SS = red_ss[0][lrow] + red_ss[1][lrow] + red_ss[2][lrow] + red_ss[3][lrow];
                float mn = S * (1.f / H_DIM);
                float var = SS * (1.f / H_DIM) - mn * mn;
                float rstd = rsqrtf(var + 1e-5f);
                #pragma unroll
                for (int j = 0; j < 4; j++) {
                    int col = wn0 + j * 16 + l15;
                    float v = acc[i][j][r] + bcol[j];
                    float o = fmaxf((v - mn) * rstd * gcol[j] + becol[j], 0.f);
                    C[(size_t)row * H_DIM + col] = f2b(o);
                }
            }
        }
    }
}

// -------- fp8 gather (wave-per-node, 16B lane, packed-f32 accumulate) --------

template<int F, bool DO_LN>
__global__ __launch_bounds__(256) void gather_f8(const unsigned char* __restrict__ xw,
                                                 unsigned short* __restrict__ out,
                                                 const int* __restrict__ rowptr,
                                                 const unsigned short* __restrict__ csr_src,
                                                 const float* __restrict__ dinv,
                                                 const float* __restrict__ bias,
                                                 const float* __restrict__ gamma,
                                                 const float* __restrict__ beta, int n) {
    constexpr int LPR = F / 16;     // lanes per row
    constexpr int G   = 64 / LPR;   // edges per load group
    int wave = threadIdx.x >> 6, lane = threadIdx.x & 63;
    int node = blockIdx.x * 4 + wave;
    if (node >= n) return;
    int r = lane / LPR;
    int p = lane % LPR;
    int beg = rowptr[node], end = rowptr[node + 1];
    const unsigned char* xwp = xw + (size_t)p * 16;
    float2v acc2[8];
    #pragma unroll
    for (int k = 0; k < 8; k++) acc2[k] = (float2v){0.f, 0.f};

    for (int base = beg; base < end; base += 64) {
        int m = end - base; if (m > 64) m = 64;
        int s_reg = 0; float w_reg = 0.f;
        if (lane < m) { s_reg = (int)csr_src[base + lane]; w_reg = dinv[s_reg]; }
        int groups = (m + G - 1) / G;
        int j = 0;
        for (; j + 4 <= groups; j += 4) {
            int e0 = j * G + r, e1 = e0 + G, e2 = e0 + 2 * G, e3 = e0 + 3 * G;
            int   s0 = __shfl(s_reg, e0, 64), s1 = __shfl(s_reg, e1, 64);
            int   s2 = __shfl(s_reg, e2, 64), s3 = __shfl(s_reg, e3, 64);
            float w0 = __shfl(w_reg, e0, 64), w1 = __shfl(w_reg, e1, 64);
            float w2 = __shfl(w_reg, e2, 64), w3 = __shfl(w_reg, e3, 64);
            uint4 v0 = *(const uint4*)(xwp + (size_t)s0 * F);
            uint4 v1 = *(const uint4*)(xwp + (size_t)s1 * F);
            uint4 v2 = *(const uint4*)(xwp + (size_t)s2 * F);
            uint4 v3 = *(const uint4*)(xwp + (size_t)s3 * F);
            accp16(acc2, v0, w0); accp16(acc2, v1, w1);
            accp16(acc2, v2, w2); accp16(acc2, v3, w3);
        }
        for (; j < groups; j++) {
            int e0 = j * G + r;
            int   s0 = __shfl(s_reg, e0, 64);
            float w0 = __shfl(w_reg, e0, 64);
            uint4 v0 = *(const uint4*)(xwp + (size_t)s0 * F);
            accp16(acc2, v0, w0);
        }
    }

    // combine edge-slot partials (over r)
    float acc[16];
    #pragma unroll
    for (int k = 0; k < 8; k++) { acc[2 * k] = acc2[k].x; acc[2 * k + 1] = acc2[k].y; }
    #pragma unroll
    for (int k = 0; k < 16; k++) {
        acc[k] += __shfl_xor(acc[k], 32, 64);
        if (LPR <= 16) acc[k] += __shfl_xor(acc[k], 16, 64);
        if (LPR <= 8)  acc[k] += __shfl_xor(acc[k], 8, 64);
    }

    float d = dinv[node];
    uint4 vo = *(const uint4*)(xw + (size_t)node * F + p * 16);
    float sv[16];
    decf8x16(sv, vo);
    float v[16];
    #pragma unroll
    for (int k = 0; k < 16; k++) v[k] = d * (acc[k] + d * sv[k]);

    if (DO_LN) {
        #pragma unroll
        for (int q = 0; q < 4; q++) {
            float4 bi = ((const float4*)bias)[p * 4 + q];
            v[q * 4 + 0] += bi.x; v[q * 4 + 1] += bi.y;
            v[q * 4 + 2] += bi.z; v[q * 4 + 3] += bi.w;
        }
        float s = 0.f, ss = 0.f;
        #pragma unroll
        for (int k = 0; k < 16; k++) { s += v[k]; ss += v[k] * v[k]; }
        #pragma unroll
        for (int o = 1; o < LPR; o <<= 1) {
            s  += __shfl_xor(s, o, 64);
            ss += __shfl_xor(ss, o, 64);
        }
        float mn = s * (1.f / F);
        float var = ss * (1.f / F) - mn * mn;
        float rstd = rsqrtf(var + 1e-5f);
        #pragma unroll
        for (int q = 0; q < 4; q++) {
            float4 ga = ((const float4*)gamma)[p * 4 + q];
            float4 be = ((const float4*)beta)[p * 4 + q];
            v[q * 4 + 0] = fmaxf((v[q * 4 + 0] - mn) * rstd * ga.x + be.x, 0.f);
            v[q * 4 + 1] = fmaxf((v[q * 4 + 1] - mn) * rstd * ga.y + be.y, 0.f);
            v[q * 4 + 2] = fmaxf((v[q * 4 + 2] - mn) * rstd * ga.z + be.z, 0.f);
            v[q * 4 + 3] = fmaxf((v[q * 4 + 3] - mn) * rstd * ga.w + be.w, 0.f);
        }
    }

    if (r == 0) {
        uint4 o0, o1;
        o0.x = (unsigned int)f2b(v[0])  | ((unsigned int)f2b(v[1])  << 16);
        o0.y = (unsigned int)f2b(v[2])  | ((unsigned int)f2b(v[3])  << 16);
        o0.z = (unsigned int)f2b(v[4])  | ((unsigned int)f2b(v[5])  << 16);
        o0.w = (unsigned int)f2b(v[6])  | ((unsigned int)f2b(v[7])  << 16);
        o1.x = (unsigned int)f2b(v[8])  | ((unsigned int)f2b(v[9])  << 16);
        o1.y = (unsigned int)f2b(v[10]) | ((unsigned int)f2b(v[11]) << 16);
        o1.z = (unsigned int)f2b(v[12]) | ((unsigned int)f2b(v[13]) << 16);
        o1.w = (unsigned int)f2b(v[14]) | ((unsigned int)f2b(v[15]) << 16);
        *(uint4*)(out + (size_t)node * F + p * 16) = o0;
        *(uint4*)(out + (size_t)node * F + p * 16 + 8) = o1;
    }
}

// ---------------- pooling ----------------

__global__ __launch_bounds__(256) void pool_kernel(const __hip_bfloat16* __restrict__ h,
                                                   const int* __restrict__ batch,
                                                   float* __restrict__ pooled, int n) {
    int t = threadIdx.x;
    int start = blockIdx.x * 64;
    int end = min(start + 64, n);
    if (start >= n) return;
    int cur = batch[start];
    float acc = 0.f;
    for (int i = start; i < end; ++i) {
        int g = batch[i];
        if (g != cur) {
            atomicAdd(&pooled[(size_t)cur * H_DIM + t], acc);
            acc = 0.f;
            cur = g;
        }
        acc += __bfloat162float(h[(size_t)i * H_DIM + t]);
    }
    atomicAdd(&pooled[(size_t)cur * H_DIM + t], acc);
}

// ---------------- FC head ----------------

__global__ __launch_bounds__(256) void fc_kernel(const float* __restrict__ pooled,
                                                 const int* __restrict__ gstart,
                                                 const float* __restrict__ gattr,
                                                 const float* __restrict__ fcW1,
                                                 const float* __restrict__ fcb1,
                                                 const float* __restrict__ fcW2,
                                                 const float* __restrict__ fcb2,
                                                 float* __restrict__ out) {
    __shared__ float zc[H_DIM + A_DIM];
    __shared__ float z1[H_DIM];
    int g = blockIdx.x, t = threadIdx.x;
    int c_i = gstart[g + 1] - gstart[g];
    float c = (float)(c_i > 1 ? c_i : 1);
    zc[t] = pooled[(size_t)g * H_DIM + t] / c;
    if (t < A_DIM) zc[H_DIM + t] = gattr[g * A_DIM + t];
    __syncthreads();
    float s = fcb1[t];
    for (int k = 0; k < H_DIM + A_DIM; k++)
        s += zc[k] * fcW1[(size_t)k * H_DIM + t];
    z1[t] = fmaxf(s, 0.f) * fcW2[t];
    __syncthreads();
    for (int off = 128; off; off >>= 1) {
        if (t < off) z1[t] += z1[t + off];
        __syncthreads();
    }
    if (t == 0) out[g] = z1[0] + fcb2[0];
}

// ---------------- launch ----------------

extern "C" void kernel_launch(void* const* d_in, const int* in_sizes, int n_in,
                              void* d_out, int out_size, void* d_ws, size_t ws_size,
                              hipStream_t stream) {
    const float* x     = (const float*)d_in[0];
    const float* gattr = (const float*)d_in[1];
    const int*   ei    = (const int*)d_in[2];
    const int*   batch = (const int*)d_in[3];
    const float* W1 = (const float*)d_in[4];  const float* b1 = (const float*)d_in[5];
    const float* W2 = (const float*)d_in[6];  const float* b2 = (const float*)d_in[7];
    const float* W3 = (const float*)d_in[8];  const float* b3 = (const float*)d_in[9];
    const float* g1 = (const float*)d_in[10]; const float* be1 = (const float*)d_in[11];
    const float* g2 = (const float*)d_in[12]; const float* be2 = (const float*)d_in[13];
    const float* g3 = (const float*)d_in[14]; const float* be3 = (const float*)d_in[15];
    const float* fcW1 = (const float*)d_in[16]; const float* fcb1 = (const float*)d_in[17];
    const float* fcW2 = (const float*)d_in[18]; const float* fcb2 = (const float*)d_in[19];
    float* out = (float*)d_out;

    char* w = (char*)d_ws;
    unsigned char*  Pb8 = (unsigned char*)w;  w += (size_t)N_NODES * H_DIM;       // xw fp8
    unsigned short* Hb  = (unsigned short*)w; w += (size_t)N_NODES * H_DIM * 2;   // h bf16
    unsigned char*  Xb8 = (unsigned char*)w;  w += (size_t)N_NODES * F_IN;        // x fp8
    unsigned short* AXb = (unsigned short*)w; w += (size_t)N_NODES * F_IN * 2;    // A·x bf16
    unsigned short* Wt1 = (unsigned short*)w; w += (size_t)H_DIM * F_IN * 2;
    unsigned short* Wt2 = (unsigned short*)w; w += (size_t)H_DIM * H_DIM * 2;
    unsigned short* Wt3 = (unsigned short*)w; w += (size_t)H_DIM * H_DIM * 2;
    float* dinv   = (float*)w; w += (size_t)N_NODES * 4;
    float* pooled = (float*)w; w += (size_t)G_NUM * H_DIM * 4;
    int* indeg    = (int*)w;   w += (size_t)N_NODES * 4;
    int* rowptr   = (int*)w;   w += (size_t)(N_NODES + 1) * 4;
    int* pos      = (int*)w;   w += (size_t)N_NODES * 4;
    unsigned short* csr_src = (unsigned short*)w; w += (size_t)N_EDGES * 2;
    int* gstart   = (int*)w;   w += (size_t)(G_NUM + 1) * 4;
    int* bsum     = (int*)w;   w += (size_t)256 * 4;

    const int* srcp = ei;
    const int* dstp = ei + N_EDGES;
    const int n_sblk = (N_NODES + 255) / 256;   // 196

    // ---- init: indeg + conversions in one overlapped dispatch ----
    hipMemsetAsync(indeg, 0, (size_t)N_NODES * sizeof(int), stream);
    {
        const int EB = (N_EDGES + 255) / 256;
        int conv_tot = N_NODES * F_IN / 4 + F_IN * H_DIM + 2 * H_DIM * H_DIM;
        int CB = (conv_tot + 255) / 256;
        init_kernel<<<EB + CB, 256, 0, stream>>>(dstp, indeg, (const float4*)x,
                                                 (unsigned int*)Xb8, W1, Wt1, W2, Wt2, W3, Wt3);
    }
    scan1_kernel<<<n_sblk, 256, 0, stream>>>(indeg, rowptr, bsum, dinv, N_NODES);
    scan2_kernel<<<1, 256, 0, stream>>>(bsum, n_sblk, batch, gstart, pooled);
    scan3_kernel<<<n_sblk, 256, 0, stream>>>(rowptr, bsum, pos, N_NODES);
    place_kernel<<<(N_EDGES + 255) / 256, 256, 0, stream>>>(srcp, dstp, pos, csr_src, N_EDGES);

    int gemm_blocks = (N_NODES + 127) / 128;
    int gather_blocks = (N_NODES + 3) / 4;

    // ---- layer 1: (A·X)·W1 with fused bias+LN+ReLU epilogue ----
    gather_f8<F_IN, false><<<gather_blocks, 256, 0, stream>>>(Xb8, AXb, rowptr, csr_src, dinv,
                                                              nullptr, nullptr, nullptr, N_NODES);
    gemm_ln<<<gemm_blocks, 512, 0, stream>>>(AXb, Wt1, Hb, b1, g1, be1, N_NODES, F_IN);

    // ---- layer 2 ----
    gemm_f8<<<gemm_blocks, 512, 0, stream>>>(Hb, Wt2, Pb8, N_NODES, H_DIM);
    gather_f8<H_DIM, true><<<gather_blocks, 256, 0, stream>>>(Pb8, Hb, rowptr, csr_src, dinv,
                                                              b2, g2, be2, N_NODES);
    // ---- layer 3 ----
    gemm_f8<<<gemm_blocks, 512, 0, stream>>>(Hb, Wt3, Pb8, N_NODES, H_DIM);
    gather_f8<H_DIM, true><<<gather_blocks, 256, 0, stream>>>(Pb8, Hb, rowptr, csr_src, dinv,
                                                              b3, g3, be3, N_NODES);

    // ---- pool + FC head ----
    pool_kernel<<<(N_NODES + 63) / 64, 256, 0, stream>>>((const __hip_bfloat16*)Hb, batch, pooled, N_NODES);
    fc_kernel<<<G_NUM, 256, 0, stream>>>(pooled, gstart, gattr, fcW1, fcb1, fcW2, fcb2, out);
}